// Round 2
// baseline (469.394 us; speedup 1.0000x reference)
//
#include <hip/hip_runtime.h>
#include <cstdint>
#include <cmath>

#define B 64
#define T 2048
#define LSTM_DIM 1024
#define ATTN_DIM 128
#define N_FILT 32
#define KSZ 31
#define ENC_DIM 512
#define PADW 15

#define TILE 128          // t-tile for energies kernel
#define AWLEN (TILE + 2*PADW)   // 158
#define LOCPAD 36         // padded leading dim for loc tile
#define NC 32             // context t-chunks
#define TC (T / NC)       // 64

__device__ __forceinline__ float fast_tanh(float x) {
    // 1 - 2/(1+exp(2x)); saturates correctly (x->+inf => 1, x->-inf => -1)
    return 1.f - 2.f / (1.f + __expf(2.f * x));
}

// ---------------- kernel 0: pq partials = decoder_q @ query_w, k-sliced ----
__global__ __launch_bounds__(128) void k_pq(const float* __restrict__ q,
                                            const float* __restrict__ Wq,
                                            float* __restrict__ pq_part) {
    int b = blockIdx.x >> 3;   // 64
    int s = blockIdx.x & 7;    // 8 k-slices of 128
    int d = threadIdx.x;       // 128
    const float* qr = q + b * LSTM_DIM + s * 128;
    const float* wr = Wq + (size_t)(s * 128) * ATTN_DIM + d;
    float acc = 0.f;
#pragma unroll 8
    for (int k = 0; k < 128; ++k)
        acc += qr[k] * wr[(size_t)k * ATTN_DIM];
    pq_part[(b * 8 + s) * ATTN_DIM + d] = acc;
}

// ---------------- kernel 1: fused conv -> proj -> tanh -> dot(v) ----------
__global__ __launch_bounds__(256) void k_energy(
        const float* __restrict__ pm,       // [B,T,128]
        const float* __restrict__ aw,       // [B,2,T]
        const uint8_t* __restrict__ mask,   // [B,T]
        const float* __restrict__ cw,       // [32,2,31]
        const float* __restrict__ proj,     // [32,128]
        const float* __restrict__ vw,       // [128]
        const float* __restrict__ pq_part,  // [B,8,128]
        float* __restrict__ energies) {     // [B,T]
    __shared__ float aw_s[2 * AWLEN];            // 316 f
    __shared__ float cw_s[N_FILT * 2 * KSZ];     // 1984 f
    __shared__ float proj_s[N_FILT * ATTN_DIM];  // 4096 f
    __shared__ float loc_s[TILE * LOCPAD];       // 4608 f
    __shared__ float pq_s[ATTN_DIM];
    __shared__ float v_s[ATTN_DIM];

    int b  = blockIdx.x >> 4;          // T/TILE = 16 tiles
    int t0 = (blockIdx.x & 15) * TILE;
    int tid = threadIdx.x;

    // ---- cooperative loads
    for (int i = tid; i < N_FILT * ATTN_DIM / 4; i += 256)
        ((float4*)proj_s)[i] = ((const float4*)proj)[i];
    for (int i = tid; i < N_FILT * 2 * KSZ; i += 256)
        cw_s[i] = cw[i];
    for (int i = tid; i < 2 * AWLEN; i += 256) {
        int c = i / AWLEN, j = i % AWLEN;
        int gt = t0 - PADW + j;
        aw_s[i] = (gt >= 0 && gt < T) ? aw[((size_t)b * 2 + c) * T + gt] : 0.f;
    }
    if (tid < ATTN_DIM) {
        float s = 0.f;
#pragma unroll
        for (int p = 0; p < 8; ++p) s += pq_part[(b * 8 + p) * ATTN_DIM + tid];
        pq_s[tid] = s;
        v_s[tid]  = vw[tid];
    }
    __syncthreads();

    // ---- phase B: conv1d -> loc_s[t][f]  (thread owns one f, 16 t's)
    {
        int f  = tid & 31;
        int g  = tid >> 5;    // 0..7
        int tb = g * 16;
        float acc[16];
#pragma unroll
        for (int i = 0; i < 16; ++i) acc[i] = 0.f;
#pragma unroll
        for (int c = 0; c < 2; ++c) {
            float awr[46];
#pragma unroll
            for (int j = 0; j < 46; ++j) awr[j] = aw_s[c * AWLEN + tb + j];
#pragma unroll
            for (int k = 0; k < KSZ; ++k) {
                float cv = cw_s[(f * 2 + c) * KSZ + k];
#pragma unroll
                for (int i = 0; i < 16; ++i) acc[i] += awr[i + k] * cv;
            }
        }
#pragma unroll
        for (int i = 0; i < 16; ++i) loc_s[(tb + i) * LOCPAD + f] = acc[i];
    }
    __syncthreads();

    // ---- phase C: energies. wave handles 4 t's at a time; lane = float2 of d
    int wave = tid >> 6, lane = tid & 63;
    const float2* pq2   = (const float2*)pq_s;
    const float2* v2v   = (const float2*)v_s;
    const float2* proj2 = (const float2*)proj_s;
    float2 pqv = pq2[lane];
    float2 vv  = v2v[lane];
    const float2* pmb = (const float2*)pm + ((size_t)b * T + t0) * (ATTN_DIM / 2);

    for (int g = 0; g < 8; ++g) {
        int tg = (g * 4 + wave) * 4;   // base local-t of this wave's group of 4
        // hoist the 4 pm loads (latency overlaps the LDS work below)
        float2 pmv0 = pmb[(size_t)(tg + 0) * 64 + lane];
        float2 pmv1 = pmb[(size_t)(tg + 1) * 64 + lane];
        float2 pmv2 = pmb[(size_t)(tg + 2) * 64 + lane];
        float2 pmv3 = pmb[(size_t)(tg + 3) * 64 + lane];

        float2 lp0 = {0.f, 0.f}, lp1 = {0.f, 0.f}, lp2 = {0.f, 0.f}, lp3 = {0.f, 0.f};
#pragma unroll
        for (int f4 = 0; f4 < 8; ++f4) {
            float4 l0 = *(const float4*)&loc_s[(tg + 0) * LOCPAD + f4 * 4];
            float4 l1 = *(const float4*)&loc_s[(tg + 1) * LOCPAD + f4 * 4];
            float4 l2 = *(const float4*)&loc_s[(tg + 2) * LOCPAD + f4 * 4];
            float4 l3 = *(const float4*)&loc_s[(tg + 3) * LOCPAD + f4 * 4];
#pragma unroll
            for (int ff = 0; ff < 4; ++ff) {
                float2 pj = proj2[(f4 * 4 + ff) * 64 + lane];
                float a0 = ((const float*)&l0)[ff];
                float a1 = ((const float*)&l1)[ff];
                float a2 = ((const float*)&l2)[ff];
                float a3 = ((const float*)&l3)[ff];
                lp0.x += a0 * pj.x; lp0.y += a0 * pj.y;
                lp1.x += a1 * pj.x; lp1.y += a1 * pj.y;
                lp2.x += a2 * pj.x; lp2.y += a2 * pj.y;
                lp3.x += a3 * pj.x; lp3.y += a3 * pj.y;
            }
        }
#pragma unroll
        for (int j = 0; j < 4; ++j) {
            float2 lp  = (j == 0) ? lp0 : (j == 1) ? lp1 : (j == 2) ? lp2 : lp3;
            float2 pmv = (j == 0) ? pmv0 : (j == 1) ? pmv1 : (j == 2) ? pmv2 : pmv3;
            float a0 = pqv.x + pmv.x + lp.x;
            float a1 = pqv.y + pmv.y + lp.y;
            float e  = vv.x * fast_tanh(a0) + vv.y * fast_tanh(a1);
#pragma unroll
            for (int off = 32; off > 0; off >>= 1)
                e += __shfl_xor(e, off);
            if (lane == 0) {
                int gt = t0 + tg + j;
                energies[(size_t)b * T + gt] = mask[(size_t)b * T + gt] ? -INFINITY : e;
            }
        }
    }
}

// ---------------- kernel 2: row softmax --------------------------------
__global__ __launch_bounds__(256) void k_softmax(const float* __restrict__ energies,
                                                 float* __restrict__ wout) {
    int b = blockIdx.x;
    int tid = threadIdx.x;
    int wave = tid >> 6, lane = tid & 63;
    __shared__ float red[8];

    float v[8];
    float m = -INFINITY;
#pragma unroll
    for (int i = 0; i < 8; ++i) {
        v[i] = energies[(size_t)b * T + tid + i * 256];
        m = fmaxf(m, v[i]);
    }
#pragma unroll
    for (int off = 32; off > 0; off >>= 1)
        m = fmaxf(m, __shfl_xor(m, off));
    if (lane == 0) red[wave] = m;
    __syncthreads();
    m = fmaxf(fmaxf(red[0], red[1]), fmaxf(red[2], red[3]));

    float s = 0.f;
#pragma unroll
    for (int i = 0; i < 8; ++i) {
        v[i] = __expf(v[i] - m);
        s += v[i];
    }
#pragma unroll
    for (int off = 32; off > 0; off >>= 1)
        s += __shfl_xor(s, off);
    if (lane == 0) red[4 + wave] = s;
    __syncthreads();
    s = (red[4] + red[5]) + (red[6] + red[7]);
    float inv = 1.f / s;
#pragma unroll
    for (int i = 0; i < 8; ++i)
        wout[(size_t)b * T + tid + i * 256] = v[i] * inv;
}

// ---------------- kernel 3: context partials ---------------------------
// 128 threads/block: lane d4 owns one float4 of the 512-wide row (16B/lane,
// a wave-pair covers a full 2KB row -> 1KB per wave per VMEM instruction).
__global__ __launch_bounds__(128) void k_ctx(const float* __restrict__ mem,
                                             const float* __restrict__ w,
                                             float* __restrict__ part) {
    int b = blockIdx.x >> 5;   // NC = 32 chunks
    int c = blockIdx.x & 31;
    int tid = threadIdx.x;     // 128: float4 over 512 enc dims
    __shared__ float w_s[TC];
    if (tid < TC) w_s[tid] = w[(size_t)b * T + c * TC + tid];
    __syncthreads();

    const float4* mrow = (const float4*)mem + ((size_t)b * T + c * TC) * (ENC_DIM / 4);
    float4 acc0 = {0.f, 0.f, 0.f, 0.f};
    float4 acc1 = {0.f, 0.f, 0.f, 0.f};
#pragma unroll 4
    for (int t = 0; t < TC; t += 2) {
        float w0  = w_s[t];
        float w1  = w_s[t + 1];
        float4 m0 = mrow[(size_t)t       * (ENC_DIM / 4) + tid];
        float4 m1 = mrow[(size_t)(t + 1) * (ENC_DIM / 4) + tid];
        acc0.x += w0 * m0.x; acc0.y += w0 * m0.y;
        acc0.z += w0 * m0.z; acc0.w += w0 * m0.w;
        acc1.x += w1 * m1.x; acc1.y += w1 * m1.y;
        acc1.z += w1 * m1.z; acc1.w += w1 * m1.w;
    }
    float4 acc = {acc0.x + acc1.x, acc0.y + acc1.y,
                  acc0.z + acc1.z, acc0.w + acc1.w};
    ((float4*)part)[((size_t)b * NC + c) * (ENC_DIM / 4) + tid] = acc;
}

// ---------------- kernel 4: reduce context partials --------------------
__global__ __launch_bounds__(128) void k_ctx_reduce(const float* __restrict__ part,
                                                    float* __restrict__ ctx) {
    int b = blockIdx.x;
    int tid = threadIdx.x;     // 128: float4 over 512 enc dims
    const float4* p = (const float4*)part + (size_t)b * NC * (ENC_DIM / 4) + tid;
    float4 acc = {0.f, 0.f, 0.f, 0.f};
#pragma unroll
    for (int c = 0; c < NC; ++c) {
        float4 v = p[(size_t)c * (ENC_DIM / 4)];
        acc.x += v.x; acc.y += v.y; acc.z += v.z; acc.w += v.w;
    }
    ((float4*)ctx)[(size_t)b * (ENC_DIM / 4) + tid] = acc;
}

extern "C" void kernel_launch(void* const* d_in, const int* in_sizes, int n_in,
                              void* d_out, int out_size, void* d_ws, size_t ws_size,
                              hipStream_t stream) {
    const float*   q    = (const float*)d_in[0];    // [B,1024]
    const float*   mem  = (const float*)d_in[1];    // [B,T,512]
    const float*   pm   = (const float*)d_in[2];    // [B,T,128]
    const float*   aw   = (const float*)d_in[3];    // [B,2,T]
    const uint8_t* mask = (const uint8_t*)d_in[4];  // [B,T] bool
    const float*   cw   = (const float*)d_in[5];    // [32,2,31]
    const float*   proj = (const float*)d_in[6];    // [32,128]
    const float*   Wq   = (const float*)d_in[7];    // [1024,128]
    const float*   vw   = (const float*)d_in[8];    // [128]

    float* out     = (float*)d_out;
    float* ctx_out = out;                    // [B,512]
    float* w_out   = out + B * ENC_DIM;      // [B,T]

    float* ws       = (float*)d_ws;
    float* pq_part  = ws;                          // B*8*128   = 65536 f
    float* energies = pq_part + B * 8 * ATTN_DIM;  // B*T       = 131072 f
    float* ctx_part = energies + (size_t)B * T;    // B*NC*512  = 1048576 f

    k_pq<<<B * 8, 128, 0, stream>>>(q, Wq, pq_part);
    k_energy<<<B * (T / TILE), 256, 0, stream>>>(pm, aw, mask, cw, proj, vw,
                                                 pq_part, energies);
    k_softmax<<<B, 256, 0, stream>>>(energies, w_out);
    k_ctx<<<B * NC, 128, 0, stream>>>(mem, w_out, ctx_part);
    k_ctx_reduce<<<B, 128, 0, stream>>>(ctx_part, ctx_out);
}